// Round 14
// baseline (339.275 us; speedup 1.0000x reference)
//
#include <hip/hip_runtime.h>

#define IN_F 256
#define HID1 128
#define HID2 64

typedef __bf16 bf16x8 __attribute__((ext_vector_type(8)));
typedef float f32x4 __attribute__((ext_vector_type(4)));
typedef unsigned short ushort8 __attribute__((ext_vector_type(8)));
typedef unsigned long long u64;

__device__ inline unsigned short f2bf(float f) {
    unsigned int u = __float_as_uint(f);
    u += 0x7fffu + ((u >> 16) & 1u);   // round-to-nearest-even
    return (unsigned short)(u >> 16);
}
__device__ inline float bf2f(unsigned short u) {
    return __uint_as_float(((unsigned int)u) << 16);
}

// ---------------- index-format detection ----------------
__global__ void detect_kernel(const int* __restrict__ e, long long nOdd, int* flag) {
    long long stride = (long long)gridDim.x * blockDim.x;
    for (long long i = (long long)blockIdx.x * blockDim.x + threadIdx.x; i < nOdd; i += stride) {
        if (e[2 * i + 1] != 0) { *flag = 1; return; }
    }
}

__device__ inline int edge_src(const void* e, const int is32, long long i, int E) {
    return is32 ? ((const int*)e)[i] : (int)((const long long*)e)[i];
}
__device__ inline int edge_dst(const void* e, const int is32, long long i, int E) {
    return is32 ? ((const int*)e)[E + i] : (int)((const long long*)e)[E + i];
}

// ---------------- degree count, dst-windowed (cnt window L2-resident per pass) ------------
__global__ void indeg_kernel(const void* __restrict__ e, const int* __restrict__ flag,
                             int* __restrict__ cnt, int E, int lo, int hi) {
    const int is32 = *flag;
    long long stride = (long long)gridDim.x * blockDim.x;
    for (long long i = (long long)blockIdx.x * blockDim.x + threadIdx.x; i < E; i += stride) {
        int d = edge_dst(e, is32, i, E);
        if (d >= lo && d < hi) atomicAdd(&cnt[d], 1);
    }
}

__global__ void dinv_kernel(const int* __restrict__ cnt, float* __restrict__ dinv, int N) {
    int i = blockIdx.x * blockDim.x + threadIdx.x;
    if (i < N) dinv[i] = rsqrtf((float)(cnt[i] + 1));
}

// ---------------- exclusive scan ----------------
__global__ __launch_bounds__(256) void scan1_kernel(const int* __restrict__ cnt,
                                                    int* __restrict__ excl,
                                                    int* __restrict__ bsum, int N) {
    __shared__ int wsums[4];
    __shared__ int wpre[4];
    const int t = threadIdx.x;
    const int base = blockIdx.x * 2048 + t * 8;
    int v[8];
    int s = 0;
#pragma unroll
    for (int j = 0; j < 8; j++) {
        v[j] = (base + j < N) ? cnt[base + j] : 0;
        s += v[j];
    }
    const int lane = t & 63;
    int x = s;
#pragma unroll
    for (int off = 1; off < 64; off <<= 1) {
        int y = __shfl_up(x, off, 64);
        if (lane >= off) x += y;
    }
    if (lane == 63) wsums[t >> 6] = x;
    __syncthreads();
    if (t == 0) {
        int r = 0;
        for (int w = 0; w < 4; w++) { wpre[w] = r; r += wsums[w]; }
    }
    __syncthreads();
    int run = wpre[t >> 6] + x - s;
#pragma unroll
    for (int j = 0; j < 8; j++) {
        if (base + j < N) excl[base + j] = run;
        run += v[j];
    }
    if (t == 255) bsum[blockIdx.x] = wpre[3] + wsums[3];
}

__global__ void scan2_kernel(int* bsum, int NB) {
    if (threadIdx.x == 0 && blockIdx.x == 0) {
        int r = 0;
        for (int i = 0; i < NB; i++) { int t = bsum[i]; bsum[i] = r; r += t; }
        bsum[NB] = r;
    }
}

__global__ void scan3_kernel(const int* __restrict__ excl, const int* __restrict__ bsum,
                             int* __restrict__ rowptr, int* __restrict__ cursor, int N) {
    int i = blockIdx.x * blockDim.x + threadIdx.x;
    if (i < N) {
        int rp = excl[i] + bsum[i >> 11];
        rowptr[i] = rp;
        cursor[i] = rp;
    } else if (i == N) {
        rowptr[N] = bsum[(N + 2047) >> 11];
    }
}

// ---------------- CSR fill, dst-windowed (write region L2-resident per pass) ----------
__global__ void fill_kernel(const void* __restrict__ e, const int* __restrict__ flag,
                            const float* __restrict__ dinv, int* __restrict__ cursor,
                            u64* __restrict__ cw, int E, int lo, int hi) {
    const int is32 = *flag;
    long long stride = (long long)gridDim.x * blockDim.x;
    for (long long i = (long long)blockIdx.x * blockDim.x + threadIdx.x; i < E; i += stride) {
        int d = edge_dst(e, is32, i, E);
        if (d < lo || d >= hi) continue;
        int s = edge_src(e, is32, i, E);
        if ((unsigned)s >= 0x80000000u) continue;
        int pos = atomicAdd(&cursor[d], 1);
        cw[pos] = ((u64)__float_as_uint(dinv[s]) << 32) | (unsigned int)s;
    }
}

// ---------------- Wt bf16 prep: Wbt[col][k] = bf16(W[k][col]) ----------------
__global__ void wbt_kernel(const float* __restrict__ W, unsigned short* __restrict__ Wbt,
                           int K, int C) {
    int t = blockIdx.x * 256 + threadIdx.x;
    if (t >= K * C) return;
    int c = t / K;
    int k = t - c * K;
    Wbt[t] = f2bf(W[k * C + c]);
}

// ---------------- GEMM1 MFMA: h1b[N,128](bf16) = x[N,256] @ W1[256,128] ----------------
__global__ __launch_bounds__(256) void gemm1_mfma_kernel(const float* __restrict__ x,
                                                         const unsigned short* __restrict__ Wbt,
                                                         unsigned short* __restrict__ hb, int N) {
    __shared__ unsigned short As[64 * 64];    // [row][k] swizzled
    __shared__ unsigned short Bs[128 * 64];   // [col][k] swizzled
    const int t = threadIdx.x;
    const int w = t >> 6;
    const int l = t & 63;
    const int lrow = l & 15;
    const int g = l >> 4;
    const int row0 = blockIdx.x * 64;

    f32x4 acc[4][2];
#pragma unroll
    for (int m = 0; m < 4; m++)
#pragma unroll
        for (int n = 0; n < 2; n++) acc[m][n] = (f32x4){0.f, 0.f, 0.f, 0.f};

    for (int kc = 0; kc < 4; kc++) {
        __syncthreads();
#pragma unroll
        for (int it = 0; it < 2; it++) {
            int slot = it * 256 + t;
            int r = slot >> 3;
            int k0 = (slot & 7) * 8;
            int grow = row0 + r;
            float4 v0 = make_float4(0.f, 0.f, 0.f, 0.f), v1 = v0;
            if (grow < N) {
                const float* p = &x[(long long)grow * IN_F + kc * 64 + k0];
                v0 = *(const float4*)p;
                v1 = *(const float4*)(p + 4);
            }
            ushort8 u;
            u[0] = f2bf(v0.x); u[1] = f2bf(v0.y); u[2] = f2bf(v0.z); u[3] = f2bf(v0.w);
            u[4] = f2bf(v1.x); u[5] = f2bf(v1.y); u[6] = f2bf(v1.z); u[7] = f2bf(v1.w);
            *(ushort8*)&As[r * 64 + (k0 ^ ((r & 7) << 3))] = u;
        }
#pragma unroll
        for (int it = 0; it < 4; it++) {
            int slot = it * 256 + t;
            int c = slot >> 3;
            int k0 = (slot & 7) * 8;
            ushort8 u = *(const ushort8*)&Wbt[c * IN_F + kc * 64 + k0];
            *(ushort8*)&Bs[c * 64 + (k0 ^ ((c & 7) << 3))] = u;
        }
        __syncthreads();
#pragma unroll
        for (int ks = 0; ks < 2; ks++) {
            int kk = ks * 32 + g * 8;
            bf16x8 af[4], bfr[2];
#pragma unroll
            for (int m = 0; m < 4; m++) {
                int r = m * 16 + lrow;
                af[m] = *(bf16x8*)&As[r * 64 + (kk ^ ((r & 7) << 3))];
            }
#pragma unroll
            for (int n = 0; n < 2; n++) {
                int c = w * 32 + n * 16 + lrow;
                bfr[n] = *(bf16x8*)&Bs[c * 64 + (kk ^ ((c & 7) << 3))];
            }
#pragma unroll
            for (int m = 0; m < 4; m++)
#pragma unroll
                for (int n = 0; n < 2; n++)
                    acc[m][n] = __builtin_amdgcn_mfma_f32_16x16x32_bf16(af[m], bfr[n], acc[m][n], 0, 0, 0);
        }
    }
#pragma unroll
    for (int m = 0; m < 4; m++) {
        int rbase = row0 + m * 16 + g * 4;
#pragma unroll
        for (int j = 0; j < 4; j++) {
            int grow = rbase + j;
            if (grow < N) {
#pragma unroll
                for (int n = 0; n < 2; n++)
                    hb[(long long)grow * HID1 + w * 32 + n * 16 + lrow] = f2bf(acc[m][n][j]);
            }
        }
    }
}

// ---------------- GEMM2 MFMA: h2b[N,64](bf16) = agg1b[N,128](bf16) @ W2[128,64] -----------
__global__ __launch_bounds__(256) void gemm2_mfma_kernel(const unsigned short* __restrict__ ab,
                                                         const unsigned short* __restrict__ Wbt,
                                                         unsigned short* __restrict__ hb, int N) {
    __shared__ unsigned short As[64 * 64];
    __shared__ unsigned short Bs[64 * 64];
    const int t = threadIdx.x;
    const int w = t >> 6;
    const int l = t & 63;
    const int lrow = l & 15;
    const int g = l >> 4;
    const int row0 = blockIdx.x * 64;

    f32x4 acc[4];
#pragma unroll
    for (int m = 0; m < 4; m++) acc[m] = (f32x4){0.f, 0.f, 0.f, 0.f};

    for (int kc = 0; kc < 2; kc++) {
        __syncthreads();
#pragma unroll
        for (int it = 0; it < 2; it++) {
            int slot = it * 256 + t;
            int r = slot >> 3;
            int k0 = (slot & 7) * 8;
            int grow = row0 + r;
            ushort8 u = (ushort8){0, 0, 0, 0, 0, 0, 0, 0};
            if (grow < N)
                u = *(const ushort8*)&ab[(long long)grow * HID1 + kc * 64 + k0];
            *(ushort8*)&As[r * 64 + (k0 ^ ((r & 7) << 3))] = u;
        }
#pragma unroll
        for (int it = 0; it < 2; it++) {
            int slot = it * 256 + t;
            int c = slot >> 3;
            int k0 = (slot & 7) * 8;
            ushort8 u = *(const ushort8*)&Wbt[c * HID1 + kc * 64 + k0];
            *(ushort8*)&Bs[c * 64 + (k0 ^ ((c & 7) << 3))] = u;
        }
        __syncthreads();
#pragma unroll
        for (int ks = 0; ks < 2; ks++) {
            int kk = ks * 32 + g * 8;
            bf16x8 af[4], bfr;
#pragma unroll
            for (int m = 0; m < 4; m++) {
                int r = m * 16 + lrow;
                af[m] = *(bf16x8*)&As[r * 64 + (kk ^ ((r & 7) << 3))];
            }
            {
                int c = w * 16 + lrow;
                bfr = *(bf16x8*)&Bs[c * 64 + (kk ^ ((c & 7) << 3))];
            }
#pragma unroll
            for (int m = 0; m < 4; m++)
                acc[m] = __builtin_amdgcn_mfma_f32_16x16x32_bf16(af[m], bfr, acc[m], 0, 0, 0);
        }
    }
#pragma unroll
    for (int m = 0; m < 4; m++) {
        int rbase = row0 + m * 16 + g * 4;
#pragma unroll
        for (int j = 0; j < 4; j++) {
            int grow = rbase + j;
            if (grow < N)
                hb[(long long)grow * HID2 + w * 16 + lrow] = f2bf(acc[m][j]);
        }
    }
}

// ---------------- CSR gather (bf16 features, packed u64 edges, 4-wide unroll) -------------
template <int G, bool RELUBF>
__global__ __launch_bounds__(256) void gather_bf16_kernel(const unsigned short* __restrict__ hb,
                                                          const float* __restrict__ bias,
                                                          const float* __restrict__ dinv,
                                                          const int* __restrict__ rowptr,
                                                          const u64* __restrict__ cw,
                                                          void* __restrict__ out, int N) {
    long long tid = (long long)blockIdx.x * 256 + threadIdx.x;
    int node = (int)(tid / G);
    int g = (int)(tid % G);
    if (node >= N) return;
    const ushort8* h8 = (const ushort8*)hb;
    float di = dinv[node];
    ushort8 hv = h8[(long long)node * G + g];
    float sum[8];
#pragma unroll
    for (int j = 0; j < 8; j++) sum[j] = di * bf2f(hv[j]);
    int p0 = rowptr[node], p1 = rowptr[node + 1];
    int p = p0;
    for (; p + 3 < p1; p += 4) {
        u64 c0 = cw[p], c1 = cw[p + 1], c2 = cw[p + 2], c3 = cw[p + 3];
        float w0 = __uint_as_float((unsigned int)(c0 >> 32));
        float w1 = __uint_as_float((unsigned int)(c1 >> 32));
        float w2 = __uint_as_float((unsigned int)(c2 >> 32));
        float w3 = __uint_as_float((unsigned int)(c3 >> 32));
        ushort8 v0 = h8[(long long)(unsigned int)c0 * G + g];
        ushort8 v1 = h8[(long long)(unsigned int)c1 * G + g];
        ushort8 v2 = h8[(long long)(unsigned int)c2 * G + g];
        ushort8 v3 = h8[(long long)(unsigned int)c3 * G + g];
#pragma unroll
        for (int j = 0; j < 8; j++)
            sum[j] += (w0 * bf2f(v0[j]) + w1 * bf2f(v1[j])) +
                      (w2 * bf2f(v2[j]) + w3 * bf2f(v3[j]));
    }
    for (; p < p1; p++) {
        u64 c0 = cw[p];
        float w0 = __uint_as_float((unsigned int)(c0 >> 32));
        ushort8 v0 = h8[(long long)(unsigned int)c0 * G + g];
#pragma unroll
        for (int j = 0; j < 8; j++) sum[j] += w0 * bf2f(v0[j]);
    }
    float4 b0 = ((const float4*)bias)[g * 2];
    float4 b1 = ((const float4*)bias)[g * 2 + 1];
    float r[8];
    r[0] = b0.x + di * sum[0]; r[1] = b0.y + di * sum[1];
    r[2] = b0.z + di * sum[2]; r[3] = b0.w + di * sum[3];
    r[4] = b1.x + di * sum[4]; r[5] = b1.y + di * sum[5];
    r[6] = b1.z + di * sum[6]; r[7] = b1.w + di * sum[7];
    if (RELUBF) {
        ushort8 u;
#pragma unroll
        for (int j = 0; j < 8; j++) u[j] = f2bf(fmaxf(r[j], 0.f));
        ((ushort8*)out)[(long long)node * G + g] = u;
    } else {
        float4 o0 = make_float4(r[0], r[1], r[2], r[3]);
        float4 o1 = make_float4(r[4], r[5], r[6], r[7]);
        float4* op = (float4*)((float*)out + ((long long)node * G + g) * 8);
        op[0] = o0;
        op[1] = o1;
    }
}

extern "C" void kernel_launch(void* const* d_in, const int* in_sizes, int n_in,
                              void* d_out, int out_size, void* d_ws, size_t ws_size,
                              hipStream_t stream) {
    const float* x  = (const float*)d_in[0];
    const void*  ei = d_in[1];
    const float* W1 = (const float*)d_in[2];
    const float* b1 = (const float*)d_in[3];
    const float* W2 = (const float*)d_in[4];
    const float* b2 = (const float*)d_in[5];
    float* out = (float*)d_out;

    const int N = in_sizes[0] / IN_F;          // 100000
    const int E = in_sizes[1] / 2;             // 1600000
    const int NB = (N + 2047) / 2048;

    char* ws = (char*)d_ws;
    size_t off = 0;
    auto alloc = [&](size_t bytes) -> char* {
        char* p = ws + off;
        off = (off + bytes + 255) & ~(size_t)255;
        return p;
    };
    int*   flag   = (int*)alloc(4);
    int*   cnt    = (int*)alloc((size_t)N * 4);
    float* dinv   = (float*)alloc((size_t)N * 4);
    int*   rowptr = (int*)alloc((size_t)(N + 1) * 4);
    int*   cursor = (int*)alloc((size_t)N * 4);
    int*   excl   = (int*)alloc((size_t)N * 4);
    int*   bsum   = (int*)alloc((size_t)(NB + 1) * 4);
    u64*   cw     = (u64*)alloc((size_t)E * 8);
    unsigned short* w1bt  = (unsigned short*)alloc((size_t)HID1 * IN_F * 2);
    unsigned short* w2bt  = (unsigned short*)alloc((size_t)HID2 * HID1 * 2);
    unsigned short* h1b   = (unsigned short*)alloc((size_t)N * HID1 * 2);  // bf16
    unsigned short* agg1b = (unsigned short*)alloc((size_t)N * HID1 * 2);  // bf16 (relu'd)
    unsigned short* h2b   = (unsigned short*)alloc((size_t)N * HID2 * 2);  // bf16

    hipMemsetAsync(flag, 0, sizeof(int), stream);
    hipMemsetAsync(cnt, 0, (size_t)N * 4, stream);

    detect_kernel<<<1024, 256, 0, stream>>>((const int*)ei, (long long)E, flag);

    const int W = 4;
    // dst-windowed indeg: cnt window (~100KB) L2-resident per pass
    for (int p = 0; p < W; p++) {
        int lo = (int)((long long)N * p / W);
        int hi = (int)((long long)N * (p + 1) / W);
        indeg_kernel<<<2048, 256, 0, stream>>>(ei, flag, cnt, E, lo, hi);
    }
    dinv_kernel<<<(N + 255) / 256, 256, 0, stream>>>(cnt, dinv, N);

    scan1_kernel<<<NB, 256, 0, stream>>>(cnt, excl, bsum, N);
    scan2_kernel<<<1, 64, 0, stream>>>(bsum, NB);
    scan3_kernel<<<(N + 256) / 256, 256, 0, stream>>>(excl, bsum, rowptr, cursor, N);

    // dst-windowed fill: write region L2-resident per pass
    for (int p = 0; p < W; p++) {
        int lo = (int)((long long)N * p / W);
        int hi = (int)((long long)N * (p + 1) / W);
        fill_kernel<<<2048, 256, 0, stream>>>(ei, flag, dinv, cursor, cw, E, lo, hi);
    }

    wbt_kernel<<<(HID1 * IN_F + 255) / 256, 256, 0, stream>>>(W1, w1bt, IN_F, HID1);
    wbt_kernel<<<(HID2 * HID1 + 255) / 256, 256, 0, stream>>>(W2, w2bt, HID1, HID2);

    // Layer 1: MFMA GEMM -> gather (relu+bf16 fused into epilogue)
    gemm1_mfma_kernel<<<(N + 63) / 64, 256, 0, stream>>>(x, w1bt, h1b, N);
    gather_bf16_kernel<16, true><<<(int)(((long long)N * 16 + 255) / 256), 256, 0, stream>>>(
        h1b, b1, dinv, rowptr, cw, agg1b, N);

    // Layer 2: MFMA GEMM (bf16 A) -> gather (f32 out)
    gemm2_mfma_kernel<<<(N + 63) / 64, 256, 0, stream>>>(agg1b, w2bt, h2b, N);
    gather_bf16_kernel<8, false><<<(int)(((long long)N * 8 + 255) / 256), 256, 0, stream>>>(
        h2b, b2, dinv, rowptr, cw, out, N);
}

// Round 15
// 265.133 us; speedup vs baseline: 1.2796x; 1.2796x over previous
//
#include <hip/hip_runtime.h>

#define IN_F 256
#define HID1 128
#define HID2 64

typedef __bf16 bf16x8 __attribute__((ext_vector_type(8)));
typedef float f32x4 __attribute__((ext_vector_type(4)));
typedef unsigned short ushort8 __attribute__((ext_vector_type(8)));
typedef unsigned long long u64;

__device__ inline unsigned short f2bf(float f) {
    unsigned int u = __float_as_uint(f);
    u += 0x7fffu + ((u >> 16) & 1u);   // round-to-nearest-even
    return (unsigned short)(u >> 16);
}
__device__ inline float bf2f(unsigned short u) {
    return __uint_as_float(((unsigned int)u) << 16);
}

// ---------------- index-format detection ----------------
__global__ void detect_kernel(const int* __restrict__ e, long long nOdd, int* flag) {
    long long stride = (long long)gridDim.x * blockDim.x;
    for (long long i = (long long)blockIdx.x * blockDim.x + threadIdx.x; i < nOdd; i += stride) {
        if (e[2 * i + 1] != 0) { *flag = 1; return; }
    }
}

__device__ inline int edge_src(const void* e, const int is32, long long i, int E) {
    return is32 ? ((const int*)e)[i] : (int)((const long long*)e)[i];
}
__device__ inline int edge_dst(const void* e, const int is32, long long i, int E) {
    return is32 ? ((const int*)e)[E + i] : (int)((const long long*)e)[E + i];
}

// ---------------- degree count + per-edge row position (single atomic pass) ------------
// pos[i] = old count of dst -> unique slot within row; written coalesced (cheap).
__global__ void indeg_kernel(const void* __restrict__ e, const int* __restrict__ flag,
                             int* __restrict__ cnt, int* __restrict__ pos, int N, int E) {
    const int is32 = *flag;
    long long stride = (long long)gridDim.x * blockDim.x;
    for (long long i = (long long)blockIdx.x * blockDim.x + threadIdx.x; i < E; i += stride) {
        int s = edge_src(e, is32, i, E);
        int d = edge_dst(e, is32, i, E);
        int p = -1;
        if ((unsigned)s < (unsigned)N && (unsigned)d < (unsigned)N)
            p = atomicAdd(&cnt[d], 1);
        pos[i] = p;
    }
}

__global__ void dinv_kernel(const int* __restrict__ cnt, float* __restrict__ dinv, int N) {
    int i = blockIdx.x * blockDim.x + threadIdx.x;
    if (i < N) dinv[i] = rsqrtf((float)(cnt[i] + 1));
}

// ---------------- exclusive scan ----------------
__global__ __launch_bounds__(256) void scan1_kernel(const int* __restrict__ cnt,
                                                    int* __restrict__ excl,
                                                    int* __restrict__ bsum, int N) {
    __shared__ int wsums[4];
    __shared__ int wpre[4];
    const int t = threadIdx.x;
    const int base = blockIdx.x * 2048 + t * 8;
    int v[8];
    int s = 0;
#pragma unroll
    for (int j = 0; j < 8; j++) {
        v[j] = (base + j < N) ? cnt[base + j] : 0;
        s += v[j];
    }
    const int lane = t & 63;
    int x = s;
#pragma unroll
    for (int off = 1; off < 64; off <<= 1) {
        int y = __shfl_up(x, off, 64);
        if (lane >= off) x += y;
    }
    if (lane == 63) wsums[t >> 6] = x;
    __syncthreads();
    if (t == 0) {
        int r = 0;
        for (int w = 0; w < 4; w++) { wpre[w] = r; r += wsums[w]; }
    }
    __syncthreads();
    int run = wpre[t >> 6] + x - s;
#pragma unroll
    for (int j = 0; j < 8; j++) {
        if (base + j < N) excl[base + j] = run;
        run += v[j];
    }
    if (t == 255) bsum[blockIdx.x] = wpre[3] + wsums[3];
}

__global__ void scan2_kernel(int* bsum, int NB) {
    if (threadIdx.x == 0 && blockIdx.x == 0) {
        int r = 0;
        for (int i = 0; i < NB; i++) { int t = bsum[i]; bsum[i] = r; r += t; }
        bsum[NB] = r;
    }
}

__global__ void scan3_kernel(const int* __restrict__ excl, const int* __restrict__ bsum,
                             int* __restrict__ rowptr, int N) {
    int i = blockIdx.x * blockDim.x + threadIdx.x;
    if (i < N) {
        rowptr[i] = excl[i] + bsum[i >> 11];
    } else if (i == N) {
        rowptr[N] = bsum[(N + 2047) >> 11];
    }
}

// ---------------- CSR fill, dst-windowed, ATOMIC-FREE (pos precomputed) ----------
__global__ void fill_kernel(const void* __restrict__ e, const int* __restrict__ flag,
                            const float* __restrict__ dinv, const int* __restrict__ rowptr,
                            const int* __restrict__ pos, u64* __restrict__ cw,
                            int E, int lo, int hi) {
    const int is32 = *flag;
    long long stride = (long long)gridDim.x * blockDim.x;
    for (long long i = (long long)blockIdx.x * blockDim.x + threadIdx.x; i < E; i += stride) {
        int d = edge_dst(e, is32, i, E);
        if (d < lo || d >= hi) continue;
        int p = pos[i];
        if (p < 0) continue;
        int s = edge_src(e, is32, i, E);
        cw[rowptr[d] + p] = ((u64)__float_as_uint(dinv[s]) << 32) | (unsigned int)s;
    }
}

// ---------------- Wt bf16 prep: Wbt[col][k] = bf16(W[k][col]) ----------------
__global__ void wbt_kernel(const float* __restrict__ W, unsigned short* __restrict__ Wbt,
                           int K, int C) {
    int t = blockIdx.x * 256 + threadIdx.x;
    if (t >= K * C) return;
    int c = t / K;
    int k = t - c * K;
    Wbt[t] = f2bf(W[k * C + c]);
}

// ---------------- GEMM1 MFMA: h1b[N,128](bf16) = x[N,256] @ W1[256,128] ----------------
__global__ __launch_bounds__(256) void gemm1_mfma_kernel(const float* __restrict__ x,
                                                         const unsigned short* __restrict__ Wbt,
                                                         unsigned short* __restrict__ hb, int N) {
    __shared__ unsigned short As[64 * 64];    // [row][k] swizzled
    __shared__ unsigned short Bs[128 * 64];   // [col][k] swizzled
    const int t = threadIdx.x;
    const int w = t >> 6;
    const int l = t & 63;
    const int lrow = l & 15;
    const int g = l >> 4;
    const int row0 = blockIdx.x * 64;

    f32x4 acc[4][2];
#pragma unroll
    for (int m = 0; m < 4; m++)
#pragma unroll
        for (int n = 0; n < 2; n++) acc[m][n] = (f32x4){0.f, 0.f, 0.f, 0.f};

    for (int kc = 0; kc < 4; kc++) {
        __syncthreads();
#pragma unroll
        for (int it = 0; it < 2; it++) {
            int slot = it * 256 + t;
            int r = slot >> 3;
            int k0 = (slot & 7) * 8;
            int grow = row0 + r;
            float4 v0 = make_float4(0.f, 0.f, 0.f, 0.f), v1 = v0;
            if (grow < N) {
                const float* p = &x[(long long)grow * IN_F + kc * 64 + k0];
                v0 = *(const float4*)p;
                v1 = *(const float4*)(p + 4);
            }
            ushort8 u;
            u[0] = f2bf(v0.x); u[1] = f2bf(v0.y); u[2] = f2bf(v0.z); u[3] = f2bf(v0.w);
            u[4] = f2bf(v1.x); u[5] = f2bf(v1.y); u[6] = f2bf(v1.z); u[7] = f2bf(v1.w);
            *(ushort8*)&As[r * 64 + (k0 ^ ((r & 7) << 3))] = u;
        }
#pragma unroll
        for (int it = 0; it < 4; it++) {
            int slot = it * 256 + t;
            int c = slot >> 3;
            int k0 = (slot & 7) * 8;
            ushort8 u = *(const ushort8*)&Wbt[c * IN_F + kc * 64 + k0];
            *(ushort8*)&Bs[c * 64 + (k0 ^ ((c & 7) << 3))] = u;
        }
        __syncthreads();
#pragma unroll
        for (int ks = 0; ks < 2; ks++) {
            int kk = ks * 32 + g * 8;
            bf16x8 af[4], bfr[2];
#pragma unroll
            for (int m = 0; m < 4; m++) {
                int r = m * 16 + lrow;
                af[m] = *(bf16x8*)&As[r * 64 + (kk ^ ((r & 7) << 3))];
            }
#pragma unroll
            for (int n = 0; n < 2; n++) {
                int c = w * 32 + n * 16 + lrow;
                bfr[n] = *(bf16x8*)&Bs[c * 64 + (kk ^ ((c & 7) << 3))];
            }
#pragma unroll
            for (int m = 0; m < 4; m++)
#pragma unroll
                for (int n = 0; n < 2; n++)
                    acc[m][n] = __builtin_amdgcn_mfma_f32_16x16x32_bf16(af[m], bfr[n], acc[m][n], 0, 0, 0);
        }
    }
#pragma unroll
    for (int m = 0; m < 4; m++) {
        int rbase = row0 + m * 16 + g * 4;
#pragma unroll
        for (int j = 0; j < 4; j++) {
            int grow = rbase + j;
            if (grow < N) {
#pragma unroll
                for (int n = 0; n < 2; n++)
                    hb[(long long)grow * HID1 + w * 32 + n * 16 + lrow] = f2bf(acc[m][n][j]);
            }
        }
    }
}

// ---------------- GEMM2 MFMA: h2b[N,64](bf16) = agg1b[N,128](bf16) @ W2[128,64] -----------
__global__ __launch_bounds__(256) void gemm2_mfma_kernel(const unsigned short* __restrict__ ab,
                                                         const unsigned short* __restrict__ Wbt,
                                                         unsigned short* __restrict__ hb, int N) {
    __shared__ unsigned short As[64 * 64];
    __shared__ unsigned short Bs[64 * 64];
    const int t = threadIdx.x;
    const int w = t >> 6;
    const int l = t & 63;
    const int lrow = l & 15;
    const int g = l >> 4;
    const int row0 = blockIdx.x * 64;

    f32x4 acc[4];
#pragma unroll
    for (int m = 0; m < 4; m++) acc[m] = (f32x4){0.f, 0.f, 0.f, 0.f};

    for (int kc = 0; kc < 2; kc++) {
        __syncthreads();
#pragma unroll
        for (int it = 0; it < 2; it++) {
            int slot = it * 256 + t;
            int r = slot >> 3;
            int k0 = (slot & 7) * 8;
            int grow = row0 + r;
            ushort8 u = (ushort8){0, 0, 0, 0, 0, 0, 0, 0};
            if (grow < N)
                u = *(const ushort8*)&ab[(long long)grow * HID1 + kc * 64 + k0];
            *(ushort8*)&As[r * 64 + (k0 ^ ((r & 7) << 3))] = u;
        }
#pragma unroll
        for (int it = 0; it < 2; it++) {
            int slot = it * 256 + t;
            int c = slot >> 3;
            int k0 = (slot & 7) * 8;
            ushort8 u = *(const ushort8*)&Wbt[c * HID1 + kc * 64 + k0];
            *(ushort8*)&Bs[c * 64 + (k0 ^ ((c & 7) << 3))] = u;
        }
        __syncthreads();
#pragma unroll
        for (int ks = 0; ks < 2; ks++) {
            int kk = ks * 32 + g * 8;
            bf16x8 af[4], bfr;
#pragma unroll
            for (int m = 0; m < 4; m++) {
                int r = m * 16 + lrow;
                af[m] = *(bf16x8*)&As[r * 64 + (kk ^ ((r & 7) << 3))];
            }
            {
                int c = w * 16 + lrow;
                bfr = *(bf16x8*)&Bs[c * 64 + (kk ^ ((c & 7) << 3))];
            }
#pragma unroll
            for (int m = 0; m < 4; m++)
                acc[m] = __builtin_amdgcn_mfma_f32_16x16x32_bf16(af[m], bfr, acc[m], 0, 0, 0);
        }
    }
#pragma unroll
    for (int m = 0; m < 4; m++) {
        int rbase = row0 + m * 16 + g * 4;
#pragma unroll
        for (int j = 0; j < 4; j++) {
            int grow = rbase + j;
            if (grow < N)
                hb[(long long)grow * HID2 + w * 16 + lrow] = f2bf(acc[m][j]);
        }
    }
}

// ---------------- CSR gather (bf16 features, packed u64 edges, 4-wide unroll) -------------
template <int G, bool RELUBF>
__global__ __launch_bounds__(256) void gather_bf16_kernel(const unsigned short* __restrict__ hb,
                                                          const float* __restrict__ bias,
                                                          const float* __restrict__ dinv,
                                                          const int* __restrict__ rowptr,
                                                          const u64* __restrict__ cw,
                                                          void* __restrict__ out, int N) {
    long long tid = (long long)blockIdx.x * 256 + threadIdx.x;
    int node = (int)(tid / G);
    int g = (int)(tid % G);
    if (node >= N) return;
    const ushort8* h8 = (const ushort8*)hb;
    float di = dinv[node];
    ushort8 hv = h8[(long long)node * G + g];
    float sum[8];
#pragma unroll
    for (int j = 0; j < 8; j++) sum[j] = di * bf2f(hv[j]);
    int p0 = rowptr[node], p1 = rowptr[node + 1];
    int p = p0;
    for (; p + 3 < p1; p += 4) {
        u64 c0 = cw[p], c1 = cw[p + 1], c2 = cw[p + 2], c3 = cw[p + 3];
        float w0 = __uint_as_float((unsigned int)(c0 >> 32));
        float w1 = __uint_as_float((unsigned int)(c1 >> 32));
        float w2 = __uint_as_float((unsigned int)(c2 >> 32));
        float w3 = __uint_as_float((unsigned int)(c3 >> 32));
        ushort8 v0 = h8[(long long)(unsigned int)c0 * G + g];
        ushort8 v1 = h8[(long long)(unsigned int)c1 * G + g];
        ushort8 v2 = h8[(long long)(unsigned int)c2 * G + g];
        ushort8 v3 = h8[(long long)(unsigned int)c3 * G + g];
#pragma unroll
        for (int j = 0; j < 8; j++)
            sum[j] += (w0 * bf2f(v0[j]) + w1 * bf2f(v1[j])) +
                      (w2 * bf2f(v2[j]) + w3 * bf2f(v3[j]));
    }
    for (; p < p1; p++) {
        u64 c0 = cw[p];
        float w0 = __uint_as_float((unsigned int)(c0 >> 32));
        ushort8 v0 = h8[(long long)(unsigned int)c0 * G + g];
#pragma unroll
        for (int j = 0; j < 8; j++) sum[j] += w0 * bf2f(v0[j]);
    }
    float4 b0 = ((const float4*)bias)[g * 2];
    float4 b1 = ((const float4*)bias)[g * 2 + 1];
    float r[8];
    r[0] = b0.x + di * sum[0]; r[1] = b0.y + di * sum[1];
    r[2] = b0.z + di * sum[2]; r[3] = b0.w + di * sum[3];
    r[4] = b1.x + di * sum[4]; r[5] = b1.y + di * sum[5];
    r[6] = b1.z + di * sum[6]; r[7] = b1.w + di * sum[7];
    if (RELUBF) {
        ushort8 u;
#pragma unroll
        for (int j = 0; j < 8; j++) u[j] = f2bf(fmaxf(r[j], 0.f));
        ((ushort8*)out)[(long long)node * G + g] = u;
    } else {
        float4 o0 = make_float4(r[0], r[1], r[2], r[3]);
        float4 o1 = make_float4(r[4], r[5], r[6], r[7]);
        float4* op = (float4*)((float*)out + ((long long)node * G + g) * 8);
        op[0] = o0;
        op[1] = o1;
    }
}

extern "C" void kernel_launch(void* const* d_in, const int* in_sizes, int n_in,
                              void* d_out, int out_size, void* d_ws, size_t ws_size,
                              hipStream_t stream) {
    const float* x  = (const float*)d_in[0];
    const void*  ei = d_in[1];
    const float* W1 = (const float*)d_in[2];
    const float* b1 = (const float*)d_in[3];
    const float* W2 = (const float*)d_in[4];
    const float* b2 = (const float*)d_in[5];
    float* out = (float*)d_out;

    const int N = in_sizes[0] / IN_F;          // 100000
    const int E = in_sizes[1] / 2;             // 1600000
    const int NB = (N + 2047) / 2048;

    char* ws = (char*)d_ws;
    size_t off = 0;
    auto alloc = [&](size_t bytes) -> char* {
        char* p = ws + off;
        off = (off + bytes + 255) & ~(size_t)255;
        return p;
    };
    int*   flag   = (int*)alloc(4);
    int*   cnt    = (int*)alloc((size_t)N * 4);
    float* dinv   = (float*)alloc((size_t)N * 4);
    int*   rowptr = (int*)alloc((size_t)(N + 1) * 4);
    int*   pos    = (int*)alloc((size_t)E * 4);
    int*   excl   = (int*)alloc((size_t)N * 4);
    int*   bsum   = (int*)alloc((size_t)(NB + 1) * 4);
    u64*   cw     = (u64*)alloc((size_t)E * 8);
    unsigned short* w1bt  = (unsigned short*)alloc((size_t)HID1 * IN_F * 2);
    unsigned short* w2bt  = (unsigned short*)alloc((size_t)HID2 * HID1 * 2);
    unsigned short* h1b   = (unsigned short*)alloc((size_t)N * HID1 * 2);  // bf16
    unsigned short* agg1b = (unsigned short*)alloc((size_t)N * HID1 * 2);  // bf16 (relu'd)
    unsigned short* h2b   = (unsigned short*)alloc((size_t)N * HID2 * 2);  // bf16

    hipMemsetAsync(flag, 0, sizeof(int), stream);
    hipMemsetAsync(cnt, 0, (size_t)N * 4, stream);

    detect_kernel<<<1024, 256, 0, stream>>>((const int*)ei, (long long)E, flag);

    // single atomic pass: counts + per-edge row positions
    indeg_kernel<<<2048, 256, 0, stream>>>(ei, flag, cnt, pos, N, E);
    dinv_kernel<<<(N + 255) / 256, 256, 0, stream>>>(cnt, dinv, N);

    scan1_kernel<<<NB, 256, 0, stream>>>(cnt, excl, bsum, N);
    scan2_kernel<<<1, 64, 0, stream>>>(bsum, NB);
    scan3_kernel<<<(N + 256) / 256, 256, 0, stream>>>(excl, bsum, rowptr, N);

    // dst-windowed fill, atomic-free: write region L2-resident per pass
    const int W = 4;
    for (int p = 0; p < W; p++) {
        int lo = (int)((long long)N * p / W);
        int hi = (int)((long long)N * (p + 1) / W);
        fill_kernel<<<2048, 256, 0, stream>>>(ei, flag, dinv, rowptr, pos, cw, E, lo, hi);
    }

    wbt_kernel<<<(HID1 * IN_F + 255) / 256, 256, 0, stream>>>(W1, w1bt, IN_F, HID1);
    wbt_kernel<<<(HID2 * HID1 + 255) / 256, 256, 0, stream>>>(W2, w2bt, HID1, HID2);

    // Layer 1: MFMA GEMM -> gather (relu+bf16 fused into epilogue)
    gemm1_mfma_kernel<<<(N + 63) / 64, 256, 0, stream>>>(x, w1bt, h1b, N);
    gather_bf16_kernel<16, true><<<(int)(((long long)N * 16 + 255) / 256), 256, 0, stream>>>(
        h1b, b1, dinv, rowptr, cw, agg1b, N);

    // Layer 2: MFMA GEMM (bf16 A) -> gather (f32 out)
    gemm2_mfma_kernel<<<(N + 63) / 64, 256, 0, stream>>>(agg1b, w2bt, h2b, N);
    gather_bf16_kernel<8, false><<<(int)(((long long)N * 8 + 255) / 256), 256, 0, stream>>>(
        h2b, b2, dinv, rowptr, cw, out, N);
}

// Round 16
// 203.687 us; speedup vs baseline: 1.6657x; 1.3017x over previous
//
#include <hip/hip_runtime.h>

#define IN_F 256
#define HID1 128
#define HID2 64
#define NBLK 256      // partition blocks
#define RB_LOG 9
#define RB 512        // nodes per bucket

typedef __bf16 bf16x8 __attribute__((ext_vector_type(8)));
typedef float f32x4 __attribute__((ext_vector_type(4)));
typedef unsigned short ushort8 __attribute__((ext_vector_type(8)));
typedef unsigned long long u64;

__device__ inline unsigned short f2bf(float f) {
    unsigned int u = __float_as_uint(f);
    u += 0x7fffu + ((u >> 16) & 1u);
    return (unsigned short)(u >> 16);
}
__device__ inline float bf2f(unsigned short u) {
    return __uint_as_float(((unsigned int)u) << 16);
}

// ---------------- index-format detection ----------------
__global__ void detect_kernel(const int* __restrict__ e, long long nOdd, int* flag) {
    long long stride = (long long)gridDim.x * blockDim.x;
    for (long long i = (long long)blockIdx.x * blockDim.x + threadIdx.x; i < nOdd; i += stride) {
        if (e[2 * i + 1] != 0) { *flag = 1; return; }
    }
}

__device__ inline int edge_src(const void* e, const int is32, long long i, int E) {
    return is32 ? ((const int*)e)[i] : (int)((const long long*)e)[i];
}
__device__ inline int edge_dst(const void* e, const int is32, long long i, int E) {
    return is32 ? ((const int*)e)[E + i] : (int)((const long long*)e)[E + i];
}

// ---------------- P1: per-block bucket histograms (LDS, no global atomics) ----------------
__global__ __launch_bounds__(256) void p1_count_kernel(const void* __restrict__ e,
                                                       const int* __restrict__ flag,
                                                       int* __restrict__ bhist,
                                                       int N, int E, int nbk, int chunk) {
    __shared__ int hist[256];
    const int is32 = *flag;
    const int blk = blockIdx.x;
    const int t = threadIdx.x;
    for (int j = t; j < nbk; j += 256) hist[j] = 0;
    __syncthreads();
    long long lo = (long long)blk * chunk;
    long long hi = lo + chunk; if (hi > E) hi = E;
    for (long long i = lo + t; i < hi; i += 256) {
        int s = edge_src(e, is32, i, E);
        int d = edge_dst(e, is32, i, E);
        if ((unsigned)s < (unsigned)N && (unsigned)d < (unsigned)N)
            atomicAdd(&hist[d >> RB_LOG], 1);
    }
    __syncthreads();
    for (int j = t; j < nbk; j += 256) bhist[j * NBLK + blk] = hist[j];   // bucket-major
}

// ---------------- P2a: exclusive scan of each bucket row (256 entries) ----------------
__global__ __launch_bounds__(256) void p2a_kernel(int* __restrict__ bhist, int* __restrict__ tot) {
    __shared__ int wsums[4], wpre[4];
    const int b = blockIdx.x;
    const int t = threadIdx.x;
    int v = bhist[b * NBLK + t];
    const int lane = t & 63;
    int x = v;
#pragma unroll
    for (int off = 1; off < 64; off <<= 1) {
        int y = __shfl_up(x, off, 64);
        if (lane >= off) x += y;
    }
    if (lane == 63) wsums[t >> 6] = x;
    __syncthreads();
    if (t == 0) { int r = 0; for (int w = 0; w < 4; w++) { wpre[w] = r; r += wsums[w]; } }
    __syncthreads();
    int excl = wpre[t >> 6] + x - v;
    bhist[b * NBLK + t] = excl;
    if (t == 255) tot[b] = excl + v;
}

// ---------------- P2b: scan bucket totals -> bstart; rowptr[N] ----------------
__global__ void p2b_kernel(const int* __restrict__ tot, int* __restrict__ bstart,
                           int* __restrict__ rowptr, int nbk, int N) {
    if (threadIdx.x == 0 && blockIdx.x == 0) {
        int r = 0;
        for (int i = 0; i < nbk; i++) { bstart[i] = r; r += tot[i]; }
        bstart[nbk] = r;
        rowptr[N] = r;
    }
}

// ---------------- P3: scatter edges into bucket-major ebuf (LDS cursors) ----------------
__global__ __launch_bounds__(256) void p3_scatter_kernel(const void* __restrict__ e,
                                                         const int* __restrict__ flag,
                                                         const int* __restrict__ bhist,
                                                         const int* __restrict__ bstart,
                                                         u64* __restrict__ ebuf,
                                                         int N, int E, int nbk, int chunk) {
    __shared__ int cur[256];
    const int is32 = *flag;
    const int blk = blockIdx.x;
    const int t = threadIdx.x;
    for (int j = t; j < nbk; j += 256) cur[j] = bhist[j * NBLK + blk] + bstart[j];
    __syncthreads();
    long long lo = (long long)blk * chunk;
    long long hi = lo + chunk; if (hi > E) hi = E;
    for (long long i = lo + t; i < hi; i += 256) {
        int s = edge_src(e, is32, i, E);
        int d = edge_dst(e, is32, i, E);
        if ((unsigned)s < (unsigned)N && (unsigned)d < (unsigned)N) {
            int p = atomicAdd(&cur[d >> RB_LOG], 1);
            ebuf[p] = ((u64)(unsigned)d << 32) | (unsigned)s;
        }
    }
}

// ---------------- P4: per-bucket CSR finalize (all in LDS) ----------------
__global__ __launch_bounds__(256) void p4_finalize_kernel(const u64* __restrict__ ebuf,
                                                          const int* __restrict__ bstart,
                                                          int* __restrict__ rowptr,
                                                          float* __restrict__ dinv,
                                                          int* __restrict__ col, int N) {
    __shared__ int cnt[RB];
    __shared__ int lrp[RB];
    __shared__ int wsums[4], wpre[4];
    const int b = blockIdx.x;
    const int t = threadIdx.x;
    const int e0 = bstart[b], e1 = bstart[b + 1];
    const int node0 = b << RB_LOG;
    int nn = N - node0; if (nn > RB) nn = RB;
    for (int j = t; j < RB; j += 256) cnt[j] = 0;
    __syncthreads();
    for (int i = e0 + t; i < e1; i += 256) {
        int d = (int)(ebuf[i] >> 32);
        atomicAdd(&cnt[d - node0], 1);
    }
    __syncthreads();
    // exclusive scan cnt[0..512) -> lrp (thread t owns 2t, 2t+1)
    int c0 = cnt[2 * t], c1 = cnt[2 * t + 1];
    int s = c0 + c1;
    const int lane = t & 63;
    int x = s;
#pragma unroll
    for (int off = 1; off < 64; off <<= 1) {
        int y = __shfl_up(x, off, 64);
        if (lane >= off) x += y;
    }
    if (lane == 63) wsums[t >> 6] = x;
    __syncthreads();
    if (t == 0) { int r = 0; for (int w = 0; w < 4; w++) { wpre[w] = r; r += wsums[w]; } }
    __syncthreads();
    int excl = wpre[t >> 6] + x - s;
    lrp[2 * t] = excl;
    lrp[2 * t + 1] = excl + c0;
    __syncthreads();
    for (int j = t; j < nn; j += 256) {
        rowptr[node0 + j] = e0 + lrp[j];
        dinv[node0 + j] = rsqrtf((float)(cnt[j] + 1));
    }
    __syncthreads();
    for (int i = e0 + t; i < e1; i += 256) {
        u64 rec = ebuf[i];
        int d = (int)(rec >> 32);
        int p = atomicAdd(&lrp[d - node0], 1);
        col[e0 + p] = (int)(unsigned)rec;
    }
}

// ---------------- Wt bf16 prep: Wbt[col][k] = bf16(W[k][col]) ----------------
__global__ void wbt_kernel(const float* __restrict__ W, unsigned short* __restrict__ Wbt,
                           int K, int C) {
    int t = blockIdx.x * 256 + threadIdx.x;
    if (t >= K * C) return;
    int c = t / K;
    int k = t - c * K;
    Wbt[t] = f2bf(W[k * C + c]);
}

// ---------------- GEMM1 MFMA: h1b[N,128](bf16) = x[N,256] @ W1[256,128] ----------------
__global__ __launch_bounds__(256) void gemm1_mfma_kernel(const float* __restrict__ x,
                                                         const unsigned short* __restrict__ Wbt,
                                                         unsigned short* __restrict__ hb, int N) {
    __shared__ unsigned short As[64 * 64];
    __shared__ unsigned short Bs[128 * 64];
    const int t = threadIdx.x;
    const int w = t >> 6;
    const int l = t & 63;
    const int lrow = l & 15;
    const int g = l >> 4;
    const int row0 = blockIdx.x * 64;

    f32x4 acc[4][2];
#pragma unroll
    for (int m = 0; m < 4; m++)
#pragma unroll
        for (int n = 0; n < 2; n++) acc[m][n] = (f32x4){0.f, 0.f, 0.f, 0.f};

    for (int kc = 0; kc < 4; kc++) {
        __syncthreads();
#pragma unroll
        for (int it = 0; it < 2; it++) {
            int slot = it * 256 + t;
            int r = slot >> 3;
            int k0 = (slot & 7) * 8;
            int grow = row0 + r;
            float4 v0 = make_float4(0.f, 0.f, 0.f, 0.f), v1 = v0;
            if (grow < N) {
                const float* p = &x[(long long)grow * IN_F + kc * 64 + k0];
                v0 = *(const float4*)p;
                v1 = *(const float4*)(p + 4);
            }
            ushort8 u;
            u[0] = f2bf(v0.x); u[1] = f2bf(v0.y); u[2] = f2bf(v0.z); u[3] = f2bf(v0.w);
            u[4] = f2bf(v1.x); u[5] = f2bf(v1.y); u[6] = f2bf(v1.z); u[7] = f2bf(v1.w);
            *(ushort8*)&As[r * 64 + (k0 ^ ((r & 7) << 3))] = u;
        }
#pragma unroll
        for (int it = 0; it < 4; it++) {
            int slot = it * 256 + t;
            int c = slot >> 3;
            int k0 = (slot & 7) * 8;
            ushort8 u = *(const ushort8*)&Wbt[c * IN_F + kc * 64 + k0];
            *(ushort8*)&Bs[c * 64 + (k0 ^ ((c & 7) << 3))] = u;
        }
        __syncthreads();
#pragma unroll
        for (int ks = 0; ks < 2; ks++) {
            int kk = ks * 32 + g * 8;
            bf16x8 af[4], bfr[2];
#pragma unroll
            for (int m = 0; m < 4; m++) {
                int r = m * 16 + lrow;
                af[m] = *(bf16x8*)&As[r * 64 + (kk ^ ((r & 7) << 3))];
            }
#pragma unroll
            for (int n = 0; n < 2; n++) {
                int c = w * 32 + n * 16 + lrow;
                bfr[n] = *(bf16x8*)&Bs[c * 64 + (kk ^ ((c & 7) << 3))];
            }
#pragma unroll
            for (int m = 0; m < 4; m++)
#pragma unroll
                for (int n = 0; n < 2; n++)
                    acc[m][n] = __builtin_amdgcn_mfma_f32_16x16x32_bf16(af[m], bfr[n], acc[m][n], 0, 0, 0);
        }
    }
#pragma unroll
    for (int m = 0; m < 4; m++) {
        int rbase = row0 + m * 16 + g * 4;
#pragma unroll
        for (int j = 0; j < 4; j++) {
            int grow = rbase + j;
            if (grow < N) {
#pragma unroll
                for (int n = 0; n < 2; n++)
                    hb[(long long)grow * HID1 + w * 32 + n * 16 + lrow] = f2bf(acc[m][n][j]);
            }
        }
    }
}

// ---------------- GEMM2 MFMA: h2b[N,64](bf16) = agg1b[N,128](bf16) @ W2[128,64] -----------
__global__ __launch_bounds__(256) void gemm2_mfma_kernel(const unsigned short* __restrict__ ab,
                                                         const unsigned short* __restrict__ Wbt,
                                                         unsigned short* __restrict__ hb, int N) {
    __shared__ unsigned short As[64 * 64];
    __shared__ unsigned short Bs[64 * 64];
    const int t = threadIdx.x;
    const int w = t >> 6;
    const int l = t & 63;
    const int lrow = l & 15;
    const int g = l >> 4;
    const int row0 = blockIdx.x * 64;

    f32x4 acc[4];
#pragma unroll
    for (int m = 0; m < 4; m++) acc[m] = (f32x4){0.f, 0.f, 0.f, 0.f};

    for (int kc = 0; kc < 2; kc++) {
        __syncthreads();
#pragma unroll
        for (int it = 0; it < 2; it++) {
            int slot = it * 256 + t;
            int r = slot >> 3;
            int k0 = (slot & 7) * 8;
            int grow = row0 + r;
            ushort8 u = (ushort8){0, 0, 0, 0, 0, 0, 0, 0};
            if (grow < N)
                u = *(const ushort8*)&ab[(long long)grow * HID1 + kc * 64 + k0];
            *(ushort8*)&As[r * 64 + (k0 ^ ((r & 7) << 3))] = u;
        }
#pragma unroll
        for (int it = 0; it < 2; it++) {
            int slot = it * 256 + t;
            int c = slot >> 3;
            int k0 = (slot & 7) * 8;
            ushort8 u = *(const ushort8*)&Wbt[c * HID1 + kc * 64 + k0];
            *(ushort8*)&Bs[c * 64 + (k0 ^ ((c & 7) << 3))] = u;
        }
        __syncthreads();
#pragma unroll
        for (int ks = 0; ks < 2; ks++) {
            int kk = ks * 32 + g * 8;
            bf16x8 af[4], bfr;
#pragma unroll
            for (int m = 0; m < 4; m++) {
                int r = m * 16 + lrow;
                af[m] = *(bf16x8*)&As[r * 64 + (kk ^ ((r & 7) << 3))];
            }
            {
                int c = w * 16 + lrow;
                bfr = *(bf16x8*)&Bs[c * 64 + (kk ^ ((c & 7) << 3))];
            }
#pragma unroll
            for (int m = 0; m < 4; m++)
                acc[m] = __builtin_amdgcn_mfma_f32_16x16x32_bf16(af[m], bfr, acc[m], 0, 0, 0);
        }
    }
#pragma unroll
    for (int m = 0; m < 4; m++) {
        int rbase = row0 + m * 16 + g * 4;
#pragma unroll
        for (int j = 0; j < 4; j++) {
            int grow = rbase + j;
            if (grow < N)
                hb[(long long)grow * HID2 + w * 16 + lrow] = f2bf(acc[m][j]);
        }
    }
}

// ---------------- CSR gather (bf16 features, int col + L2 dinv table, 4-wide) -------------
template <int G, bool RELUBF>
__global__ __launch_bounds__(256) void gather_bf16_kernel(const unsigned short* __restrict__ hb,
                                                          const float* __restrict__ bias,
                                                          const float* __restrict__ dinv,
                                                          const int* __restrict__ rowptr,
                                                          const int* __restrict__ col,
                                                          void* __restrict__ out, int N) {
    long long tid = (long long)blockIdx.x * 256 + threadIdx.x;
    int node = (int)(tid / G);
    int g = (int)(tid % G);
    if (node >= N) return;
    const ushort8* h8 = (const ushort8*)hb;
    float di = dinv[node];
    ushort8 hv = h8[(long long)node * G + g];
    float sum[8];
#pragma unroll
    for (int j = 0; j < 8; j++) sum[j] = di * bf2f(hv[j]);
    int p0 = rowptr[node], p1 = rowptr[node + 1];
    int p = p0;
    for (; p + 3 < p1; p += 4) {
        int s0 = col[p], s1 = col[p + 1], s2 = col[p + 2], s3 = col[p + 3];
        float w0 = dinv[s0], w1 = dinv[s1], w2 = dinv[s2], w3 = dinv[s3];
        ushort8 v0 = h8[(long long)s0 * G + g];
        ushort8 v1 = h8[(long long)s1 * G + g];
        ushort8 v2 = h8[(long long)s2 * G + g];
        ushort8 v3 = h8[(long long)s3 * G + g];
#pragma unroll
        for (int j = 0; j < 8; j++)
            sum[j] += (w0 * bf2f(v0[j]) + w1 * bf2f(v1[j])) +
                      (w2 * bf2f(v2[j]) + w3 * bf2f(v3[j]));
    }
    for (; p < p1; p++) {
        int s0 = col[p];
        float w0 = dinv[s0];
        ushort8 v0 = h8[(long long)s0 * G + g];
#pragma unroll
        for (int j = 0; j < 8; j++) sum[j] += w0 * bf2f(v0[j]);
    }
    float4 b0 = ((const float4*)bias)[g * 2];
    float4 b1 = ((const float4*)bias)[g * 2 + 1];
    float r[8];
    r[0] = b0.x + di * sum[0]; r[1] = b0.y + di * sum[1];
    r[2] = b0.z + di * sum[2]; r[3] = b0.w + di * sum[3];
    r[4] = b1.x + di * sum[4]; r[5] = b1.y + di * sum[5];
    r[6] = b1.z + di * sum[6]; r[7] = b1.w + di * sum[7];
    if (RELUBF) {
        ushort8 u;
#pragma unroll
        for (int j = 0; j < 8; j++) u[j] = f2bf(fmaxf(r[j], 0.f));
        ((ushort8*)out)[(long long)node * G + g] = u;
    } else {
        float4 o0 = make_float4(r[0], r[1], r[2], r[3]);
        float4 o1 = make_float4(r[4], r[5], r[6], r[7]);
        float4* op = (float4*)((float*)out + ((long long)node * G + g) * 8);
        op[0] = o0;
        op[1] = o1;
    }
}

extern "C" void kernel_launch(void* const* d_in, const int* in_sizes, int n_in,
                              void* d_out, int out_size, void* d_ws, size_t ws_size,
                              hipStream_t stream) {
    const float* x  = (const float*)d_in[0];
    const void*  ei = d_in[1];
    const float* W1 = (const float*)d_in[2];
    const float* b1 = (const float*)d_in[3];
    const float* W2 = (const float*)d_in[4];
    const float* b2 = (const float*)d_in[5];
    float* out = (float*)d_out;

    const int N = in_sizes[0] / IN_F;          // 100000
    const int E = in_sizes[1] / 2;             // 1600000
    const int nbk = (N + RB - 1) >> RB_LOG;    // 196 (must be <= 256)
    const int chunk = (E + NBLK - 1) / NBLK;   // 6250

    char* ws = (char*)d_ws;
    size_t off = 0;
    auto alloc = [&](size_t bytes) -> char* {
        char* p = ws + off;
        off = (off + bytes + 255) & ~(size_t)255;
        return p;
    };
    int*   flag   = (int*)alloc(4);
    int*   bhist  = (int*)alloc((size_t)256 * NBLK * 4);
    int*   tot    = (int*)alloc(256 * 4);
    int*   bstart = (int*)alloc(257 * 4);
    float* dinv   = (float*)alloc((size_t)N * 4);
    int*   rowptr = (int*)alloc((size_t)(N + 1) * 4);
    u64*   ebuf   = (u64*)alloc((size_t)E * 8);
    int*   col    = (int*)alloc((size_t)E * 4);
    unsigned short* w1bt  = (unsigned short*)alloc((size_t)HID1 * IN_F * 2);
    unsigned short* w2bt  = (unsigned short*)alloc((size_t)HID2 * HID1 * 2);
    unsigned short* h1b   = (unsigned short*)alloc((size_t)N * HID1 * 2);
    unsigned short* agg1b = (unsigned short*)alloc((size_t)N * HID1 * 2);
    unsigned short* h2b   = (unsigned short*)alloc((size_t)N * HID2 * 2);

    hipMemsetAsync(flag, 0, sizeof(int), stream);

    detect_kernel<<<1024, 256, 0, stream>>>((const int*)ei, (long long)E, flag);

    // CSR build: bucket partition, zero global atomics
    p1_count_kernel<<<NBLK, 256, 0, stream>>>(ei, flag, bhist, N, E, nbk, chunk);
    p2a_kernel<<<nbk, 256, 0, stream>>>(bhist, tot);
    p2b_kernel<<<1, 64, 0, stream>>>(tot, bstart, rowptr, nbk, N);
    p3_scatter_kernel<<<NBLK, 256, 0, stream>>>(ei, flag, bhist, bstart, ebuf, N, E, nbk, chunk);
    p4_finalize_kernel<<<nbk, 256, 0, stream>>>(ebuf, bstart, rowptr, dinv, col, N);

    wbt_kernel<<<(HID1 * IN_F + 255) / 256, 256, 0, stream>>>(W1, w1bt, IN_F, HID1);
    wbt_kernel<<<(HID2 * HID1 + 255) / 256, 256, 0, stream>>>(W2, w2bt, HID1, HID2);

    // Layer 1: MFMA GEMM -> gather (relu+bf16 fused)
    gemm1_mfma_kernel<<<(N + 63) / 64, 256, 0, stream>>>(x, w1bt, h1b, N);
    gather_bf16_kernel<16, true><<<(int)(((long long)N * 16 + 255) / 256), 256, 0, stream>>>(
        h1b, b1, dinv, rowptr, col, agg1b, N);

    // Layer 2: MFMA GEMM (bf16 A) -> gather (f32 out)
    gemm2_mfma_kernel<<<(N + 63) / 64, 256, 0, stream>>>(agg1b, w2bt, h2b, N);
    gather_bf16_kernel<8, false><<<(int)(((long long)N * 8 + 255) / 256), 256, 0, stream>>>(
        h2b, b2, dinv, rowptr, col, out, N);
}